// Round 4
// baseline (203.891 us; speedup 1.0000x reference)
//
#include <hip/hip_runtime.h>

// N=4194304 rows, C=8. Output: scalar mean(ce_loss * value).
// Memory floor: 144MB read-once -> ~23us at 6.3 TB/s. Harness adds ~146us
// of timed poison/restore (512MB ws fill @78us + d_in restore) we can't touch.
// R1: same-address atomics serialized (~200us) -> two-stage reduction.
// R2/R3: identical 54us kernel time for two different schedules -> shared
//   bottleneck is the 32B-lane-stride float4 pattern (half of each cache line
//   per instruction). R4: fully-coalesced unit-stride loads; lanes 2k,2k+1
//   cooperate on one row via shfl_xor; each row counted twice, folded into
//   the 0.5/N scale in stage2.

#define N_ROWS 4194304
#define TPB 256
#define GRID 2048
#define ROWS_PER_BLOCK (N_ROWS / GRID)   // 2048
#define ITERS (ROWS_PER_BLOCK / TPB)     // 8 iters; per iter a wave does 64 rows

// Lane pair (2k, 2k+1) holds row k's 8 logits: even lane = cols 0-3,
// odd lane = cols 4-7. Both lanes of the pair get the same t and return the
// same ce*value (row thus counted twice; stage2 scales by 0.5/N).
__device__ __forceinline__ float pair_contrib(float4 h, int t, int half) {
    // inv(T_COV) = [[2.4, 1.6],[1.6, 2.4]]        (T_COV=[[.75,-.5],[-.5,.75]])
    // inv(F_COV) = [[10.3030..,-9.6969..],[...]]  (F_COV=[[.85,.8],[.8,.85]])
    // local top-2 of my 4 elements
    float a = fmaxf(h.x, h.y), b = fminf(h.x, h.y);
    float c = fmaxf(h.z, h.w), d = fminf(h.z, h.w);
    float m1L = fmaxf(a, c);
    float m2L = fmaxf(fminf(a, c), fmaxf(b, d));
    // merge with partner lane
    float m1P = __shfl_xor(m1L, 1, 64);
    float m2P = __shfl_xor(m2L, 1, 64);
    float m1 = fmaxf(m1L, m1P);
    float m2 = fmaxf(fminf(m1L, m1P), fmaxf(m2L, m2P));
    // softmax denominator
    float sL = __expf(h.x - m1) + __expf(h.y - m1) +
               __expf(h.z - m1) + __expf(h.w - m1);
    float s = sL + __shfl_xor(sL, 1, 64);
    // x[t]: exactly one lane of the pair owns column t
    int tc = t & 3;
    float cand = h.x;
    cand = (tc == 1) ? h.y : cand;
    cand = (tc == 2) ? h.z : cand;
    cand = (tc == 3) ? h.w : cand;
    float xm = ((t >> 2) == half) ? cand : 0.0f;
    float xt = xm + __shfl_xor(xm, 1, 64);

    float inv_s = 1.0f / s;
    float logs  = __logf(s);
    float p_t   = __expf(xt - m1) * inv_s;
    float ce    = (m1 - xt) + logs;          // -logp[target]

    bool  is_t  = (xt == m1);                // p_t is the max prob
    float p2    = __expf(m2 - m1) * inv_s;   // second-max prob
    float p_neg = is_t ? p2 : inv_s;         // max prob = exp(0)/s

    float aC = is_t ? 2.4f : 10.30303030303030f;
    float bC = is_t ? 1.6f : -9.69696969696970f;
    float dx = p_t   - (is_t ? 0.5f : 0.3f);
    float dy = p_neg - (is_t ? 0.5f : 0.15f);

    float q = aC * (dx * dx + dy * dy) + 2.0f * bC * dx * dy;
    return ce * __expf(-0.5f * q);
}

// Stage 1: fully coalesced. Per iter, each wave loads 2KB contiguous
// (2x dwordx4 at unit lane stride) = 64 rows, plus 64 targets.
__global__ __launch_bounds__(TPB) void coga_stage1(
    const float4* __restrict__ x4,
    const int* __restrict__ tgt,
    float* __restrict__ partials)
{
    const int wave = threadIdx.x >> 6;
    const int lane = threadIdx.x & 63;
    const int half = lane & 1;

    const size_t block_row0 = (size_t)blockIdx.x * ROWS_PER_BLOCK;

    float acc = 0.0f;
    #pragma unroll
    for (int i = 0; i < ITERS; ++i) {
        size_t row0 = block_row0 + (size_t)i * TPB + (size_t)wave * 64;
        size_t b4 = row0 * 2;                  // float4 index of wave's chunk
        float4 h0 = x4[b4 + lane];             // rows row0 + lane/2
        float4 h1 = x4[b4 + 64 + lane];        // rows row0 + 32 + lane/2
        int t_all = tgt[row0 + lane];          // targets for all 64 rows
        int t0 = __shfl(t_all, lane >> 1, 64);
        int t1 = __shfl(t_all, 32 + (lane >> 1), 64);
        acc += pair_contrib(h0, t0, half);
        acc += pair_contrib(h1, t1, half);
    }

    // wave-64 + LDS block reduction
    #pragma unroll
    for (int off = 32; off > 0; off >>= 1)
        acc += __shfl_down(acc, off, 64);

    __shared__ float wsum[TPB / 64];
    if (lane == 0) wsum[wave] = acc;
    __syncthreads();

    if (threadIdx.x == 0) {
        float bs = 0.0f;
        #pragma unroll
        for (int w = 0; w < TPB / 64; ++w) bs += wsum[w];
        partials[blockIdx.x] = bs;
    }
}

// Stage 2: single block reduces GRID partials. Each row was summed twice
// in stage1 -> scale by 0.5/N.
__global__ __launch_bounds__(1024) void coga_stage2(
    const float* __restrict__ partials,
    float* __restrict__ out)
{
    float s = 0.0f;
    for (int i = threadIdx.x; i < GRID; i += 1024)
        s += partials[i];

    #pragma unroll
    for (int off = 32; off > 0; off >>= 1)
        s += __shfl_down(s, off, 64);

    __shared__ float wsum[1024 / 64];
    int lane = threadIdx.x & 63;
    int wid  = threadIdx.x >> 6;
    if (lane == 0) wsum[wid] = s;
    __syncthreads();

    if (threadIdx.x == 0) {
        float bs = 0.0f;
        #pragma unroll
        for (int w = 0; w < 1024 / 64; ++w) bs += wsum[w];
        out[0] = bs * (0.5f / (float)N_ROWS);
    }
}

// Fallback (ws too small): per-row loads, grid-stride + few atomics.
__device__ __forceinline__ float row_contrib(float4 v0, float4 v1, int t) {
    float m1 = v0.x, m2 = -INFINITY;
    float xs[7] = {v0.y, v0.z, v0.w, v1.x, v1.y, v1.z, v1.w};
    #pragma unroll
    for (int i = 0; i < 7; ++i) {
        float xi = xs[i];
        float hi = fmaxf(xi, m1);
        float lo = fminf(xi, m1);
        m2 = fmaxf(m2, lo);
        m1 = hi;
    }
    float s = __expf(v0.x - m1) + __expf(v0.y - m1) +
              __expf(v0.z - m1) + __expf(v0.w - m1) +
              __expf(v1.x - m1) + __expf(v1.y - m1) +
              __expf(v1.z - m1) + __expf(v1.w - m1);
    float xt = v0.x;
    xt = (t == 1) ? v0.y : xt;
    xt = (t == 2) ? v0.z : xt;
    xt = (t == 3) ? v0.w : xt;
    xt = (t == 4) ? v1.x : xt;
    xt = (t == 5) ? v1.y : xt;
    xt = (t == 6) ? v1.z : xt;
    xt = (t == 7) ? v1.w : xt;
    float inv_s = 1.0f / s;
    float p_t   = __expf(xt - m1) * inv_s;
    float ce    = (m1 - xt) + __logf(s);
    bool  is_t  = (xt == m1);
    float p_neg = is_t ? __expf(m2 - m1) * inv_s : inv_s;
    float aC = is_t ? 2.4f : 10.30303030303030f;
    float bC = is_t ? 1.6f : -9.69696969696970f;
    float dx = p_t   - (is_t ? 0.5f : 0.3f);
    float dy = p_neg - (is_t ? 0.5f : 0.15f);
    float q = aC * (dx * dx + dy * dy) + 2.0f * bC * dx * dy;
    return ce * __expf(-0.5f * q);
}

__global__ __launch_bounds__(TPB) void coga_fallback(
    const float* __restrict__ x,
    const int* __restrict__ tgt,
    float* __restrict__ out)
{
    float acc = 0.0f;
    int stride = gridDim.x * TPB;
    for (int row = blockIdx.x * TPB + threadIdx.x; row < N_ROWS; row += stride) {
        const float4* p = (const float4*)(x + (size_t)row * 8);
        acc += row_contrib(p[0], p[1], tgt[row]);
    }
    #pragma unroll
    for (int off = 32; off > 0; off >>= 1)
        acc += __shfl_down(acc, off, 64);
    __shared__ float wsum[TPB / 64];
    int lane = threadIdx.x & 63;
    int wid  = threadIdx.x >> 6;
    if (lane == 0) wsum[wid] = acc;
    __syncthreads();
    if (threadIdx.x == 0) {
        float bs = 0.0f;
        #pragma unroll
        for (int w = 0; w < TPB / 64; ++w) bs += wsum[w];
        atomicAdd(out, bs * (1.0f / (float)N_ROWS));
    }
}

extern "C" void kernel_launch(void* const* d_in, const int* in_sizes, int n_in,
                              void* d_out, int out_size, void* d_ws, size_t ws_size,
                              hipStream_t stream) {
    const float* x   = (const float*)d_in[0];
    const int*   tgt = (const int*)d_in[1];
    float*       out = (float*)d_out;

    if (ws_size >= GRID * sizeof(float)) {
        float* partials = (float*)d_ws;
        coga_stage1<<<GRID, TPB, 0, stream>>>((const float4*)x, tgt, partials);
        coga_stage2<<<1, 1024, 0, stream>>>(partials, out);
    } else {
        hipMemsetAsync(out, 0, sizeof(float), stream);
        coga_fallback<<<512, TPB, 0, stream>>>(x, tgt, out);
    }
}

// Round 5
// 200.419 us; speedup vs baseline: 1.0173x; 1.0173x over previous
//
#include <hip/hip_runtime.h>

// N=4194304 rows, C=8. Output: scalar mean(ce_loss * value).
// HBM floor: 144MB read-once -> ~22us. Harness adds ~146us timed overhead
// (512MiB d_ws poison fill @78us + d_in restore) that no kernel change touches.
// R1: 16384 same-address atomics serialize @~9.8ns each (~160us) -> keep
//     atomic count <= 512.
// R2/R3/R4: three different stage1 schedules (tiny blocks / batched strided /
//     fully coalesced pair-cooperative) all identical at ~200us total ->
//     access pattern exonerated; remaining slack is structural (stage2 node,
//     launch gaps). R5: single fused kernel, 512 blocks, 1 atomic/block.

#define N_ROWS 4194304
#define TPB 256
#define GRID 512
#define RPT (N_ROWS / (GRID * TPB))   // 32 rows per thread
#define BATCH 4

__device__ __forceinline__ float row_contrib(float4 v0, float4 v1, int t) {
    // inv(T_COV) = [[2.4, 1.6],[1.6, 2.4]]        (T_COV=[[.75,-.5],[-.5,.75]])
    // inv(F_COV) = [[10.3030..,-9.6969..],[...]]  (F_COV=[[.85,.8],[.8,.85]])
    // top-2 of logits (exp is monotone -> top-2 of probs)
    float m1 = v0.x, m2 = -INFINITY;
    float xs[7] = {v0.y, v0.z, v0.w, v1.x, v1.y, v1.z, v1.w};
    #pragma unroll
    for (int i = 0; i < 7; ++i) {
        float xi = xs[i];
        float hi = fmaxf(xi, m1);
        float lo = fminf(xi, m1);
        m2 = fmaxf(m2, lo);
        m1 = hi;
    }

    float s = __expf(v0.x - m1) + __expf(v0.y - m1) +
              __expf(v0.z - m1) + __expf(v0.w - m1) +
              __expf(v1.x - m1) + __expf(v1.y - m1) +
              __expf(v1.z - m1) + __expf(v1.w - m1);

    float xt = v0.x;
    xt = (t == 1) ? v0.y : xt;
    xt = (t == 2) ? v0.z : xt;
    xt = (t == 3) ? v0.w : xt;
    xt = (t == 4) ? v1.x : xt;
    xt = (t == 5) ? v1.y : xt;
    xt = (t == 6) ? v1.z : xt;
    xt = (t == 7) ? v1.w : xt;

    float inv_s = 1.0f / s;
    float p_t   = __expf(xt - m1) * inv_s;
    float ce    = (m1 - xt) + __logf(s);     // -logp[target]

    bool  is_t  = (xt == m1);                // p_t is the max prob
    float p_neg = is_t ? __expf(m2 - m1) * inv_s : inv_s;  // max = exp(0)/s

    float aC = is_t ? 2.4f : 10.30303030303030f;
    float bC = is_t ? 1.6f : -9.69696969696970f;
    float dx = p_t   - (is_t ? 0.5f : 0.3f);
    float dy = p_neg - (is_t ? 0.5f : 0.15f);

    float q = aC * (dx * dx + dy * dy) + 2.0f * bC * dx * dy;
    return ce * __expf(-0.5f * q);
}

// Fused: grid-stride, 32 rows/thread batched 4-wide (12 loads in flight per
// batch), block reduce, ONE atomicAdd per block (512 total, ~5us worst case
// serialization hidden in the block tail).
__global__ __launch_bounds__(TPB) void coga_fused(
    const float4* __restrict__ x4,
    const int* __restrict__ tgt,
    float* __restrict__ out)
{
    const int tid    = blockIdx.x * TPB + threadIdx.x;
    const int stride = GRID * TPB;

    float acc = 0.0f;
    for (int k = 0; k < RPT; k += BATCH) {
        float4 a0[BATCH], a1[BATCH];
        int    t[BATCH];
        #pragma unroll
        for (int j = 0; j < BATCH; ++j) {
            int row = tid + (k + j) * stride;
            a0[j] = x4[2 * (size_t)row];
            a1[j] = x4[2 * (size_t)row + 1];
            t[j]  = tgt[row];
        }
        #pragma unroll
        for (int j = 0; j < BATCH; ++j)
            acc += row_contrib(a0[j], a1[j], t[j]);
    }

    // wave-64 + LDS block reduction
    #pragma unroll
    for (int off = 32; off > 0; off >>= 1)
        acc += __shfl_down(acc, off, 64);

    __shared__ float wsum[TPB / 64];
    int lane = threadIdx.x & 63;
    int wid  = threadIdx.x >> 6;
    if (lane == 0) wsum[wid] = acc;
    __syncthreads();

    if (threadIdx.x == 0) {
        float bs = 0.0f;
        #pragma unroll
        for (int w = 0; w < TPB / 64; ++w) bs += wsum[w];
        atomicAdd(out, bs * (1.0f / (float)N_ROWS));
    }
}

extern "C" void kernel_launch(void* const* d_in, const int* in_sizes, int n_in,
                              void* d_out, int out_size, void* d_ws, size_t ws_size,
                              hipStream_t stream) {
    const float* x   = (const float*)d_in[0];
    const int*   tgt = (const int*)d_in[1];
    float*       out = (float*)d_out;

    hipMemsetAsync(out, 0, sizeof(float), stream);
    coga_fused<<<GRID, TPB, 0, stream>>>((const float4*)x, tgt, out);
}

// Round 6
// 195.396 us; speedup vs baseline: 1.0435x; 1.0257x over previous
//
#include <hip/hip_runtime.h>

// N=4194304 rows, C=8. Output: scalar mean(ce_loss * value).
// HBM floor: 144MB read-once -> ~23us. Harness adds ~146us timed overhead
// (512MiB d_ws poison fill @78us + d_in restore) that no kernel change touches.
// R1: 16384 same-address atomics serialize (~160us) -> keep atomics <= 512.
// R2-R5: FOUR different structures (tiny blocks / batched strided / coalesced
//   pair-coop / fused) all at 200+-4us -> structure exonerated; kernel ~54us
//   vs 23us floor. R6: test cache-allocation policy — nontemporal loads for
//   the read-once stream (everything else identical to R5).

#define N_ROWS 4194304
#define TPB 256
#define GRID 512
#define RPT (N_ROWS / (GRID * TPB))   // 32 rows per thread
#define BATCH 4

typedef float vf4 __attribute__((ext_vector_type(4)));

__device__ __forceinline__ float row_contrib(vf4 v0, vf4 v1, int t) {
    // inv(T_COV) = [[2.4, 1.6],[1.6, 2.4]]        (T_COV=[[.75,-.5],[-.5,.75]])
    // inv(F_COV) = [[10.3030..,-9.6969..],[...]]  (F_COV=[[.85,.8],[.8,.85]])
    // top-2 of logits (exp is monotone -> top-2 of probs)
    float m1 = v0.x, m2 = -INFINITY;
    float xs[7] = {v0.y, v0.z, v0.w, v1.x, v1.y, v1.z, v1.w};
    #pragma unroll
    for (int i = 0; i < 7; ++i) {
        float xi = xs[i];
        float hi = fmaxf(xi, m1);
        float lo = fminf(xi, m1);
        m2 = fmaxf(m2, lo);
        m1 = hi;
    }

    float s = __expf(v0.x - m1) + __expf(v0.y - m1) +
              __expf(v0.z - m1) + __expf(v0.w - m1) +
              __expf(v1.x - m1) + __expf(v1.y - m1) +
              __expf(v1.z - m1) + __expf(v1.w - m1);

    float xt = v0.x;
    xt = (t == 1) ? v0.y : xt;
    xt = (t == 2) ? v0.z : xt;
    xt = (t == 3) ? v0.w : xt;
    xt = (t == 4) ? v1.x : xt;
    xt = (t == 5) ? v1.y : xt;
    xt = (t == 6) ? v1.z : xt;
    xt = (t == 7) ? v1.w : xt;

    float inv_s = 1.0f / s;
    float p_t   = __expf(xt - m1) * inv_s;
    float ce    = (m1 - xt) + __logf(s);     // -logp[target]

    bool  is_t  = (xt == m1);                // p_t is the max prob
    float p_neg = is_t ? __expf(m2 - m1) * inv_s : inv_s;  // max = exp(0)/s

    float aC = is_t ? 2.4f : 10.30303030303030f;
    float bC = is_t ? 1.6f : -9.69696969696970f;
    float dx = p_t   - (is_t ? 0.5f : 0.3f);
    float dy = p_neg - (is_t ? 0.5f : 0.15f);

    float q = aC * (dx * dx + dy * dy) + 2.0f * bC * dx * dy;
    return ce * __expf(-0.5f * q);
}

// Fused: grid-stride, 32 rows/thread batched 4-wide, NONTEMPORAL loads
// (read-once stream, don't allocate in L2/L3), block reduce, one
// atomicAdd per block (512 total).
__global__ __launch_bounds__(TPB) void coga_fused(
    const vf4* __restrict__ x4,
    const int* __restrict__ tgt,
    float* __restrict__ out)
{
    const int tid    = blockIdx.x * TPB + threadIdx.x;
    const int stride = GRID * TPB;

    float acc = 0.0f;
    for (int k = 0; k < RPT; k += BATCH) {
        vf4 a0[BATCH], a1[BATCH];
        int t[BATCH];
        #pragma unroll
        for (int j = 0; j < BATCH; ++j) {
            int row = tid + (k + j) * stride;
            a0[j] = __builtin_nontemporal_load(&x4[2 * (size_t)row]);
            a1[j] = __builtin_nontemporal_load(&x4[2 * (size_t)row + 1]);
            t[j]  = __builtin_nontemporal_load(&tgt[row]);
        }
        #pragma unroll
        for (int j = 0; j < BATCH; ++j)
            acc += row_contrib(a0[j], a1[j], t[j]);
    }

    // wave-64 + LDS block reduction
    #pragma unroll
    for (int off = 32; off > 0; off >>= 1)
        acc += __shfl_down(acc, off, 64);

    __shared__ float wsum[TPB / 64];
    int lane = threadIdx.x & 63;
    int wid  = threadIdx.x >> 6;
    if (lane == 0) wsum[wid] = acc;
    __syncthreads();

    if (threadIdx.x == 0) {
        float bs = 0.0f;
        #pragma unroll
        for (int w = 0; w < TPB / 64; ++w) bs += wsum[w];
        atomicAdd(out, bs * (1.0f / (float)N_ROWS));
    }
}

extern "C" void kernel_launch(void* const* d_in, const int* in_sizes, int n_in,
                              void* d_out, int out_size, void* d_ws, size_t ws_size,
                              hipStream_t stream) {
    const float* x   = (const float*)d_in[0];
    const int*   tgt = (const int*)d_in[1];
    float*       out = (float*)d_out;

    hipMemsetAsync(out, 0, sizeof(float), stream);
    coga_fused<<<GRID, TPB, 0, stream>>>((const vf4*)x, tgt, out);
}